// Round 5
// baseline (5625.364 us; speedup 1.0000x reference)
//
#include <hip/hip_runtime.h>
#include <stdint.h>

typedef __bf16 bf16x8 __attribute__((ext_vector_type(8)));
typedef float f32x16 __attribute__((ext_vector_type(16)));
typedef unsigned int u32x4 __attribute__((ext_vector_type(4)));

struct Params {
  const float *x, *s_in, *Wf, *bf, *Wo, *bo, *Wi, *bi, *Wg, *bg;
  const float *Wsi, *bsi, *Wsg, *bsg;
  const float *eWih, *eWhh, *ebih, *ebhh;
  const float *dWih0, *dWhh0, *dbih0, *dbhh0;
  const float *dWih1, *dWhh1, *dbih1, *dbhh1;
  const float *fcW, *fcb;
  float* out;
  unsigned* ctrl;
  unsigned short *wpea_h, *wpea_l, *wpenc_h, *wpenc_l;
  unsigned short *wpd0_h, *wpd0_l, *wpd1_h, *wpd1_l;
  unsigned short *xp_h, *xp_l;
  float *si_v, *sg_v, *cbea, *cbenc, *cbd0, *cbd1, *w0v, *fcw, *pred;
  unsigned short *henc, *hA, *hB, *hseq;
};

#define SLOT 131072   // elems per h slot: [plane2][kp32][s256][j8]

__device__ __forceinline__ unsigned short f2bf(float f){
  unsigned u = __builtin_bit_cast(unsigned, f);
  u += 0x7FFFu + ((u >> 16) & 1u);
  return (unsigned short)(u >> 16);
}
__device__ __forceinline__ float bf2f(unsigned short h){
  return __builtin_bit_cast(float, ((unsigned)h) << 16);
}
__device__ __forceinline__ float sigm(float v){ return 1.0f / (1.0f + __expf(-v)); }
__device__ __forceinline__ float tanh_f(float v){
  float a = fabsf(v);
  float e = __expf(-2.0f * a);
  float t = (1.0f - e) / (1.0f + e);
  return __builtin_copysignf(t, v);
}

// ---- coherence-point (MALL) accessors: bypass L1/L2 so cross-block h exchange
// ---- needs NO buffer_wbl2 / buffer_inv fences anywhere in the main loop.
__device__ __forceinline__ u32x4 ldg_cc16(const unsigned short* p){
  u32x4 v;
  unsigned long long a = (unsigned long long)p;
  asm volatile("global_load_dwordx4 %0, %1, off sc0 sc1" : "=v"(v) : "v"(a) : "memory");
  return v;
}
__device__ __forceinline__ void stg_cc16(unsigned short* p, u32x4 v){
  unsigned long long a = (unsigned long long)p;
  asm volatile("global_store_dwordx4 %0, %1, off sc0 sc1" :: "v"(a), "v"(v) : "memory");
}
__device__ __forceinline__ void ldg_f32_issue(const float* p, float& d){
  unsigned long long a = (unsigned long long)p;
  asm volatile("global_load_dword %0, %1, off sc0 sc1" : "=v"(d) : "v"(a) : "memory");
}
__device__ __forceinline__ void vm_drain(){
  asm volatile("s_waitcnt vmcnt(0)" ::: "memory");
  __builtin_amdgcn_sched_barrier(0);
}

extern "C" __global__ void __launch_bounds__(256, 1) ea_lstm_fused(Params P){
  __shared__ __align__(16) unsigned short aLds[18432];   // [plane][p(<=36)][s32][j8]
  __shared__ __align__(16) float gdump[32 * 132];        // [s32][col128 +4 pad]
  __shared__ __align__(16) float redl[32 * 33];
  __shared__ __align__(16) unsigned short hstg[2 * 4 * 33 * 8]; // [plane2][kp4][s33][j8]

  const int tid = threadIdx.x;
  const int blk = blockIdx.x;
  const int sgp = blk & 7;    // sample group (XCD-affine)
  const int cbk = blk >> 3;   // column block 0..7 (128 gate cols each)
  const int lane = tid & 63;
  const int wv = tid >> 6;
  const int gtid = blk * 256 + tid;
  const int kgl = lane >> 5;
  const int aln = lane & 31;
  const int colg = cbk * 128 + wv * 32 + aln;

  // ---------------- precompute (all 64 blocks) ----------------
  {
    for (int e = gtid; e < 294912; e += 16384){           // EA weights [288 x 1024]
      int j = e & 7, kg = (e >> 3) & 1, col = (e >> 4) & 1023, kt = e >> 14;
      int k = kt * 16 + kg * 8 + j;
      int u = col >> 2, g = col & 3;
      const float* Wp = (g == 0) ? P.Wf : (g == 1) ? P.Wo : (g == 2) ? P.Wi : P.Wg;
      float w = Wp[u * 288 + k];
      unsigned short hi = f2bf(w);
      P.wpea_h[e] = hi; P.wpea_l[e] = f2bf(w - bf2f(hi));
    }
    for (int e = gtid; e < 524288; e += 16384){           // enc [512 x 1024]
      int j = e & 7, kg = (e >> 3) & 1, col = (e >> 4) & 1023, kt = e >> 14;
      int k = kt * 16 + kg * 8 + j;
      int u = col >> 2, g = col & 3, row = g * 256 + u;
      float w = (k < 256) ? P.eWih[row * 256 + k] : P.eWhh[row * 256 + (k - 256)];
      unsigned short hi = f2bf(w);
      P.wpenc_h[e] = hi; P.wpenc_l[e] = f2bf(w - bf2f(hi));
    }
    for (int e = gtid; e < 262144; e += 16384){           // dec0 [256 x 1024]
      int j = e & 7, kg = (e >> 3) & 1, col = (e >> 4) & 1023, kt = e >> 14;
      int k = kt * 16 + kg * 8 + j;
      int u = col >> 2, g = col & 3, row = g * 256 + u;
      float w = P.dWhh0[row * 256 + k];
      unsigned short hi = f2bf(w);
      P.wpd0_h[e] = hi; P.wpd0_l[e] = f2bf(w - bf2f(hi));
    }
    for (int e = gtid; e < 524288; e += 16384){           // dec1 [512 x 1024]
      int j = e & 7, kg = (e >> 3) & 1, col = (e >> 4) & 1023, kt = e >> 14;
      int k = kt * 16 + kg * 8 + j;
      int u = col >> 2, g = col & 3, row = g * 256 + u;
      float w = (k < 256) ? P.dWih1[row * 256 + k] : P.dWhh1[row * 256 + (k - 256)];
      unsigned short hi = f2bf(w);
      P.wpd1_h[e] = hi; P.wpd1_l[e] = f2bf(w - bf2f(hi));
    }
    for (int e = gtid; e < 2990080; e += 16384){          // x -> [t][kp4][s256][j8]
      int j = e & 7, sl = (e >> 3) & 255, kp = (e >> 11) & 3, t = e >> 13;
      int f = kp * 8 + j;
      float w = P.x[((size_t)sl * 365 + t) * 32 + f];
      unsigned short hi = f2bf(w);
      P.xp_h[e] = hi; P.xp_l[e] = f2bf(w - bf2f(hi));
    }
    for (int e = gtid; e < 65536; e += 16384){            // si/sg statics (incl. bi/bg)
      int u = e & 255, b = e >> 8;
      float ai = P.bsi[u] + P.bi[u];
      float ag = P.bsg[u] + P.bg[u];
      for (int k = 0; k < 27; ++k){
        float sv = P.s_in[b * 27 + k];
        ai += sv * P.Wsi[u * 27 + k];
        ag += sv * P.Wsg[u * 27 + k];
      }
      P.si_v[b * 256 + u] = ai;
      P.sg_v[b * 256 + u] = ag;
    }
    for (int e = gtid; e < 1024; e += 16384){             // col biases / vectors
      int u = e >> 2, g = e & 3, row = g * 256 + u;
      P.cbea[e] = (g == 0) ? P.bf[u] : (g == 1) ? P.bo[u] : 0.0f;
      P.cbenc[e] = P.ebih[row] + P.ebhh[row];
      P.cbd0[e]  = P.dbih0[row] + P.dbhh0[row];
      P.cbd1[e]  = P.dbih1[row] + P.dbhh1[row];
      P.w0v[e]   = P.dWih0[row];
      if (e < 256) P.fcw[e] = P.fcW[e];
    }
    for (int e = gtid; e < 6144; e += 16384) P.pred[e] = P.fcb[0];
  }

  // one-time global barrier (64 blocks, acq_rel: flushes precompute to mem-side)
  __syncthreads();
  if (tid == 0){
    unsigned n = __hip_atomic_fetch_add(P.ctrl, 1u, __ATOMIC_ACQ_REL, __HIP_MEMORY_SCOPE_AGENT) + 1u;
    if (n == 64u) __hip_atomic_store(P.ctrl + 16, 1u, __ATOMIC_RELEASE, __HIP_MEMORY_SCOPE_AGENT);
    else while (__hip_atomic_load(P.ctrl + 16, __ATOMIC_ACQUIRE, __HIP_MEMORY_SCOPE_AGENT) < 1u)
      __builtin_amdgcn_s_sleep(2);
  }
  __syncthreads();

  // ---------------- persistent phase machinery (relaxed, fence-free) ----------------
  unsigned* gctr = P.ctrl + 32 + 32 * sgp;
  unsigned gphase = 0;   // arrivals completed by THIS block

  const int u_loc = tid & 31;
  const int u_g = cbk * 32 + u_loc;
  int s_loc[4], s_g[4];
  #pragma unroll
  for (int q = 0; q < 4; ++q){ s_loc[q] = 8 * q + (tid >> 5); s_g[q] = sgp * 32 + s_loc[q]; }

  // wait until all 8 blocks of this sgp have arrived `gphase` times.
  // tid0-ONLY poll (R1 had all 256 threads hammering the line), then barrier.
  auto spinp = [&](){
    if (tid == 0){
      unsigned target = 8u * gphase;
      while (__hip_atomic_load(gctr, __ATOMIC_RELAXED, __HIP_MEMORY_SCOPE_SYSTEM) < target) {}
    }
    __syncthreads();
  };
  // arrive: h stores already issued; drain to coherence point, then count.
  auto arrive = [&](){
    vm_drain();
    __syncthreads();
    if (tid == 0) __hip_atomic_fetch_add(gctr, 1u, __ATOMIC_RELAXED, __HIP_MEMORY_SCOPE_SYSTEM);
    ++gphase;
  };

  // stage a full 32-kp h slot via coherent loads (PC=32 layout)
  auto stage32_c = [&](const unsigned short* slot){
    u32x4 v[8];
    #pragma unroll
    for (int i = 0; i < 8; ++i){
      int seg = tid + 256 * i;
      int plane = seg >> 10, rem = seg & 1023, p = rem >> 5, sl = rem & 31;
      v[i] = ldg_cc16(slot + (size_t)plane * 65536 + (p * 256 + sgp * 32 + sl) * 8);
    }
    vm_drain();
    #pragma unroll
    for (int i = 0; i < 8; ++i){
      int seg = tid + 256 * i;
      int plane = seg >> 10, rem = seg & 1023, p = rem >> 5, sl = rem & 31;
      *(u32x4*)&aLds[((plane * 32 + p) * 32 + sl) * 8] = v[i];
    }
  };
  // EA: x part (kp 0..3 of 36) — static data, plain loads, 1 uint4/thread
  auto stage_ea_x = [&](int t){
    int plane = tid >> 7, p = (tid >> 5) & 3, sl = tid & 31;
    const unsigned short* xp = plane ? P.xp_l : P.xp_h;
    uint4 v = *(const uint4*)(xp + (size_t)t * 8192 + (p * 256 + sgp * 32 + sl) * 8);
    *(uint4*)&aLds[((plane * 36 + p) * 32 + sl) * 8] = v;
  };
  // EA: h part (kp 4..35 of 36) — coherent loads, zeros at t=0
  auto stage_ea_h = [&](const unsigned short* hslot){
    if (hslot){
      u32x4 v[8];
      #pragma unroll
      for (int i = 0; i < 8; ++i){
        int seg = tid + 256 * i;
        int plane = seg >> 10, rem = seg & 1023, hp = rem >> 5, sl = rem & 31;
        v[i] = ldg_cc16(hslot + (size_t)plane * 65536 + (hp * 256 + sgp * 32 + sl) * 8);
      }
      vm_drain();
      #pragma unroll
      for (int i = 0; i < 8; ++i){
        int seg = tid + 256 * i;
        int plane = seg >> 10, rem = seg & 1023, hp = rem >> 5, sl = rem & 31;
        *(u32x4*)&aLds[((plane * 36 + 4 + hp) * 32 + sl) * 8] = v[i];
      }
    } else {
      u32x4 z = {0u, 0u, 0u, 0u};
      #pragma unroll
      for (int i = 0; i < 8; ++i){
        int seg = tid + 256 * i;
        int plane = seg >> 10, rem = seg & 1023, hp = rem >> 5, sl = rem & 31;
        *(u32x4*)&aLds[((plane * 36 + 4 + hp) * 32 + sl) * 8] = z;
      }
    }
  };

  auto mfma_chunk = [&](f32x16 acc, const unsigned short* wh, const unsigned short* wl,
                        int nkt, int kt0, int PC) -> f32x16 {
    #pragma unroll 4
    for (int kt = 0; kt < nkt; ++kt){
      int p = 2 * kt + kgl;
      bf16x8 ahi = __builtin_bit_cast(bf16x8, *(const uint4*)&aLds[((0 * PC + p) * 32 + aln) * 8]);
      bf16x8 alo = __builtin_bit_cast(bf16x8, *(const uint4*)&aLds[((1 * PC + p) * 32 + aln) * 8]);
      size_t be = ((size_t)(kt + kt0) * 1024 + colg) * 16 + kgl * 8;
      bf16x8 bhi = __builtin_bit_cast(bf16x8, *(const uint4*)(wh + be));
      bf16x8 blo = __builtin_bit_cast(bf16x8, *(const uint4*)(wl + be));
      acc = __builtin_amdgcn_mfma_f32_32x32x16_bf16(alo, bhi, acc, 0, 0, 0);
      acc = __builtin_amdgcn_mfma_f32_32x32x16_bf16(ahi, blo, acc, 0, 0, 0);
      acc = __builtin_amdgcn_mfma_f32_32x32x16_bf16(ahi, bhi, acc, 0, 0, 0);
    }
    return acc;
  };

  auto dump = [&](const f32x16& acc){
    #pragma unroll
    for (int r = 0; r < 16; ++r){
      int row = (r & 3) + 8 * (r >> 2) + 4 * kgl;    // verified C/D layout
      gdump[row * 132 + wv * 32 + aln] = acc[r];
    }
  };

  // scatter h (bf16 hi/lo) into hstg (padded s-stride 33: kills 8-way LDS
  // bank conflicts measured at 9.5M cycles in R1)
  auto h_scatter = [&](int q, float h){
    int kp = u_loc >> 3, j = u_loc & 7;
    unsigned short hi = f2bf(h);
    hstg[((0 * 4 + kp) * 33 + s_loc[q]) * 8 + j] = hi;
    hstg[((1 * 4 + kp) * 33 + s_loc[q]) * 8 + j] = f2bf(h - bf2f(hi));
  };
  // coalesced 16B coherent store of the block's h tile (call after __syncthreads)
  auto h_store = [&](unsigned short* slot){
    int plane = tid >> 7, kp = (tid >> 5) & 3, sl = tid & 31;
    u32x4 v = *(const u32x4*)&hstg[((plane * 4 + kp) * 33 + sl) * 8];
    stg_cc16(slot + (size_t)plane * 65536 + (((size_t)(cbk * 4 + kp) * 256) + sgp * 32 + sl) * 8, v);
  };

  float cbr[4];
  float cst[4] = {0.f, 0.f, 0.f, 0.f};

  // ---------------- EA phase ----------------
  {
    float sir[4], sgr[4];
    #pragma unroll
    for (int g = 0; g < 4; ++g) cbr[g] = P.cbea[4 * u_g + g];
    #pragma unroll
    for (int q = 0; q < 4; ++q){
      sir[q] = P.si_v[s_g[q] * 256 + u_g];
      sgr[q] = P.sg_v[s_g[q] * 256 + u_g];
    }
    for (int t = 0; t < 365; ++t){
      stage_ea_x(t);                      // flag-independent
      spinp();                            // wait h(t-1) from all blocks
      stage_ea_h(t ? P.hseq + (size_t)(t - 1) * SLOT : nullptr);
      __syncthreads();
      f32x16 acc;
      #pragma unroll
      for (int r = 0; r < 16; ++r) acc[r] = 0.0f;
      acc = mfma_chunk(acc, P.wpea_h, P.wpea_l, 18, 0, 36);  // single pass, K=288
      dump(acc); __syncthreads();
      #pragma unroll
      for (int q = 0; q < 4; ++q){
        float4 g4 = *(const float4*)&gdump[s_loc[q] * 132 + 4 * u_loc];
        float f = sigm(g4.x + cbr[0]);
        float o = sigm(g4.y + cbr[1]);
        float i = sigm(g4.z + sir[q]);
        float g = tanh_f(g4.w + sgr[q]);
        float c = f * cst[q] + i * g;
        cst[q] = c;
        h_scatter(q, o * tanh_f(c));
      }
      __syncthreads();
      h_store(P.hseq + (size_t)t * SLOT);
      arrive();
    }
  }

  // ---------------- encoder phase ----------------
  {
    #pragma unroll
    for (int g = 0; g < 4; ++g) cbr[g] = P.cbenc[4 * u_g + g];
    for (int t = 0; t < 365; ++t){
      // first half: Wih * ea_seq[t] — flag-independent (hseq[t] is final since EA)
      stage32_c(P.hseq + (size_t)t * SLOT); __syncthreads();
      f32x16 acc;
      #pragma unroll
      for (int r = 0; r < 16; ++r) acc[r] = 0.0f;
      acc = mfma_chunk(acc, P.wpenc_h, P.wpenc_l, 16, 0, 32);
      __syncthreads();                    // all waves done with aLds
      spinp();                            // wait h_enc(t-1)
      stage32_c(t ? P.henc + (size_t)((t - 1) & 1) * SLOT
                  : P.hseq + (size_t)364 * SLOT);
      __syncthreads();
      acc = mfma_chunk(acc, P.wpenc_h, P.wpenc_l, 16, 16, 32);
      dump(acc); __syncthreads();
      #pragma unroll
      for (int q = 0; q < 4; ++q){
        float4 g4 = *(const float4*)&gdump[s_loc[q] * 132 + 4 * u_loc];
        float i = sigm(g4.x + cbr[0]);
        float f = sigm(g4.y + cbr[1]);
        float g = tanh_f(g4.z + cbr[2]);
        float o = sigm(g4.w + cbr[3]);
        float c = f * cst[q] + i * g;
        cst[q] = c;
        h_scatter(q, o * tanh_f(c));
      }
      __syncthreads();
      h_store(P.henc + (size_t)(t & 1) * SLOT);
      arrive();
    }
  }

  // ---------------- decoder phase ----------------
  {
    float cb0r[4], cb1r[4], w0r[4];
    #pragma unroll
    for (int g = 0; g < 4; ++g){
      cb0r[g] = P.cbd0[4 * u_g + g];
      cb1r[g] = P.cbd1[4 * u_g + g];
      w0r[g]  = P.w0v[4 * u_g + g];
    }
    float fcwr = P.fcw[u_g];
    float cA[4], cB[4];
    #pragma unroll
    for (int q = 0; q < 4; ++q){ cA[q] = cst[q]; cB[q] = cst[q]; }

    spinp();   // ensure enc final h (henc slot 0) visible before t=0 staging

    for (int t = 0; t < 24; ++t){
      // ---- cell 0: entire GEMM is flag-independent (hA(t-1) two arrivals old) ----
      stage32_c(t ? P.hA + (size_t)((t - 1) & 1) * SLOT : P.henc);
      __syncthreads();
      f32x16 acc;
      #pragma unroll
      for (int r = 0; r < 16; ++r) acc[r] = 0.0f;
      acc = mfma_chunk(acc, P.wpd0_h, P.wpd0_l, 16, 0, 32);
      dump(acc); __syncthreads();
      spinp();                            // wait cell1(t-1): pred(t-1) ready
      float d0 = 0.f, d1 = 0.f, d2 = 0.f, d3 = 0.f;
      if (t){
        ldg_f32_issue(&P.pred[(t - 1) * 256 + s_g[0]], d0);
        ldg_f32_issue(&P.pred[(t - 1) * 256 + s_g[1]], d1);
        ldg_f32_issue(&P.pred[(t - 1) * 256 + s_g[2]], d2);
        ldg_f32_issue(&P.pred[(t - 1) * 256 + s_g[3]], d3);
        asm volatile("s_waitcnt vmcnt(0)" : "+v"(d0), "+v"(d1), "+v"(d2), "+v"(d3) :: "memory");
        __builtin_amdgcn_sched_barrier(0);
      }
      float din[4] = {d0, d1, d2, d3};
      #pragma unroll
      for (int q = 0; q < 4; ++q){
        float4 g4 = *(const float4*)&gdump[s_loc[q] * 132 + 4 * u_loc];
        float i = sigm(g4.x + cb0r[0] + din[q] * w0r[0]);
        float f = sigm(g4.y + cb0r[1] + din[q] * w0r[1]);
        float g = tanh_f(g4.z + cb0r[2] + din[q] * w0r[2]);
        float o = sigm(g4.w + cb0r[3] + din[q] * w0r[3]);
        float c = f * cA[q] + i * g;
        cA[q] = c;
        h_scatter(q, o * tanh_f(c));
      }
      __syncthreads();
      h_store(P.hA + (size_t)(t & 1) * SLOT);
      arrive();

      // ---- cell 1: hB(t-1) half is flag-independent; hA(t) half waits cell0(t) ----
      stage32_c(t ? P.hB + (size_t)((t - 1) & 1) * SLOT : P.henc);
      __syncthreads();
      #pragma unroll
      for (int r = 0; r < 16; ++r) acc[r] = 0.0f;
      acc = mfma_chunk(acc, P.wpd1_h, P.wpd1_l, 16, 16, 32);   // Whh1 * hB(t-1)
      __syncthreads();
      spinp();                            // wait cell0(t): hA(t) ready
      stage32_c(P.hA + (size_t)(t & 1) * SLOT);
      __syncthreads();
      acc = mfma_chunk(acc, P.wpd1_h, P.wpd1_l, 16, 0, 32);    // Wih1 * hA(t)
      dump(acc); __syncthreads();
      #pragma unroll
      for (int q = 0; q < 4; ++q){
        float4 g4 = *(const float4*)&gdump[s_loc[q] * 132 + 4 * u_loc];
        float i = sigm(g4.x + cb1r[0]);
        float f = sigm(g4.y + cb1r[1]);
        float g = tanh_f(g4.z + cb1r[2]);
        float o = sigm(g4.w + cb1r[3]);
        float c = f * cB[q] + i * g;
        cB[q] = c;
        float h = o * tanh_f(c);
        h_scatter(q, h);
        redl[u_loc * 33 + s_loc[q]] = fcwr * h;
      }
      __syncthreads();
      h_store(P.hB + (size_t)(t & 1) * SLOT);
      if (tid < 32){
        float sum = 0.0f;
        #pragma unroll
        for (int u = 0; u < 32; ++u) sum += redl[u * 33 + tid];
        __hip_atomic_fetch_add(&P.pred[t * 256 + sgp * 32 + tid], sum,
                               __ATOMIC_RELAXED, __HIP_MEMORY_SCOPE_SYSTEM);
      }
      arrive();
    }
  }

  // ---------------- output ----------------
  spinp();   // ALL blocks wait for everyone's final arrive (pred[23] complete)
  if (cbk == 0){
    for (int i = tid; i < 32 * 24; i += 256){
      int sl = i / 24, tt = i % 24;
      float v = 0.0f;
      ldg_f32_issue(&P.pred[tt * 256 + sgp * 32 + sl], v);
      asm volatile("s_waitcnt vmcnt(0)" : "+v"(v) :: "memory");
      P.out[(size_t)(sgp * 32 + sl) * 24 + tt] = v;
    }
  }
}

extern "C" void kernel_launch(void* const* d_in, const int* in_sizes, int n_in,
                              void* d_out, int out_size, void* d_ws, size_t ws_size,
                              hipStream_t stream){
  (void)in_sizes; (void)n_in; (void)out_size; (void)ws_size;
  Params P;
  P.x = (const float*)d_in[0];   P.s_in = (const float*)d_in[1];
  P.Wf = (const float*)d_in[2];  P.bf = (const float*)d_in[3];
  P.Wo = (const float*)d_in[4];  P.bo = (const float*)d_in[5];
  P.Wi = (const float*)d_in[6];  P.bi = (const float*)d_in[7];
  P.Wg = (const float*)d_in[8];  P.bg = (const float*)d_in[9];
  P.Wsi = (const float*)d_in[10]; P.bsi = (const float*)d_in[11];
  P.Wsg = (const float*)d_in[12]; P.bsg = (const float*)d_in[13];
  P.eWih = (const float*)d_in[14]; P.eWhh = (const float*)d_in[15];
  P.ebih = (const float*)d_in[16]; P.ebhh = (const float*)d_in[17];
  P.dWih0 = (const float*)d_in[18]; P.dWhh0 = (const float*)d_in[19];
  P.dbih0 = (const float*)d_in[20]; P.dbhh0 = (const float*)d_in[21];
  P.dWih1 = (const float*)d_in[22]; P.dWhh1 = (const float*)d_in[23];
  P.dbih1 = (const float*)d_in[24]; P.dbhh1 = (const float*)d_in[25];
  P.fcW = (const float*)d_in[26]; P.fcb = (const float*)d_in[27];
  P.out = (float*)d_out;

  char* base = (char*)d_ws;
  size_t off = 0;
  auto take = [&](size_t bytes) -> char* {
    char* r = base + off;
    off = (off + bytes + 255) & ~(size_t)255;
    return r;
  };
  P.ctrl    = (unsigned*)take(4096);
  P.wpea_h  = (unsigned short*)take((size_t)294912 * 2);
  P.wpea_l  = (unsigned short*)take((size_t)294912 * 2);
  P.wpenc_h = (unsigned short*)take((size_t)524288 * 2);
  P.wpenc_l = (unsigned short*)take((size_t)524288 * 2);
  P.wpd0_h  = (unsigned short*)take((size_t)262144 * 2);
  P.wpd0_l  = (unsigned short*)take((size_t)262144 * 2);
  P.wpd1_h  = (unsigned short*)take((size_t)524288 * 2);
  P.wpd1_l  = (unsigned short*)take((size_t)524288 * 2);
  P.xp_h    = (unsigned short*)take((size_t)2990080 * 2);
  P.xp_l    = (unsigned short*)take((size_t)2990080 * 2);
  P.si_v    = (float*)take((size_t)65536 * 4);
  P.sg_v    = (float*)take((size_t)65536 * 4);
  P.cbea    = (float*)take(4096);
  P.cbenc   = (float*)take(4096);
  P.cbd0    = (float*)take(4096);
  P.cbd1    = (float*)take(4096);
  P.w0v     = (float*)take(4096);
  P.fcw     = (float*)take(1024);
  P.pred    = (float*)take((size_t)6144 * 4);
  P.henc    = (unsigned short*)take((size_t)2 * 131072 * 2);
  P.hA      = (unsigned short*)take((size_t)2 * 131072 * 2);
  P.hB      = (unsigned short*)take((size_t)2 * 131072 * 2);
  P.hseq    = (unsigned short*)take((size_t)365 * 131072 * 2);

  hipMemsetAsync(d_ws, 0, 4096, stream);
  hipLaunchKernelGGL(ea_lstm_fused, dim3(64), dim3(256), 0, stream, P);
}

// Round 6
// 3800.038 us; speedup vs baseline: 1.4803x; 1.4803x over previous
//
#include <hip/hip_runtime.h>
#include <stdint.h>

typedef __bf16 bf16x8 __attribute__((ext_vector_type(8)));
typedef float f32x16 __attribute__((ext_vector_type(16)));
typedef unsigned int u32x4 __attribute__((ext_vector_type(4)));

struct Params {
  const float *x, *s_in, *Wf, *bf, *Wo, *bo, *Wi, *bi, *Wg, *bg;
  const float *Wsi, *bsi, *Wsg, *bsg;
  const float *eWih, *eWhh, *ebih, *ebhh;
  const float *dWih0, *dWhh0, *dbih0, *dbhh0;
  const float *dWih1, *dWhh1, *dbih1, *dbhh1;
  const float *fcW, *fcb;
  float* out;
  unsigned* ctrl;
  unsigned short *wpea_h, *wpea_l, *wpenc_h, *wpenc_l;
  unsigned short *wpd0_h, *wpd0_l, *wpd1_h, *wpd1_l;
  unsigned short *xp_h, *xp_l;
  float *si_v, *sg_v, *cbea, *cbenc, *cbd0, *cbd1, *w0v, *fcw, *pred;
  unsigned short *henc, *hA, *hB, *hseq;
};

#define SLOT 131072   // elems per h slot: [plane2][kp32][s256][j8]

__device__ __forceinline__ unsigned short f2bf(float f){
  unsigned u = __builtin_bit_cast(unsigned, f);
  u += 0x7FFFu + ((u >> 16) & 1u);
  return (unsigned short)(u >> 16);
}
__device__ __forceinline__ float bf2f(unsigned short h){
  return __builtin_bit_cast(float, ((unsigned)h) << 16);
}
__device__ __forceinline__ float sigm(float v){ return 1.0f / (1.0f + __expf(-v)); }
__device__ __forceinline__ float tanh_f(float v){
  float a = fabsf(v);
  float e = __expf(-2.0f * a);
  float t = (1.0f - e) / (1.0f + e);
  return __builtin_copysignf(t, v);
}

// ---- coherence-point (MALL) accessors: bypass L1/L2 so cross-block h exchange
// ---- needs NO buffer_wbl2 / buffer_inv fences anywhere in the main loop.
__device__ __forceinline__ u32x4 ldg_cc16(const unsigned short* p){
  u32x4 v;
  unsigned long long a = (unsigned long long)p;
  asm volatile("global_load_dwordx4 %0, %1, off sc0 sc1" : "=v"(v) : "v"(a) : "memory");
  return v;
}
__device__ __forceinline__ void stg_cc16(unsigned short* p, u32x4 v){
  unsigned long long a = (unsigned long long)p;
  asm volatile("global_store_dwordx4 %0, %1, off sc0 sc1" :: "v"(a), "v"(v) : "memory");
}
__device__ __forceinline__ void ldg_f32_issue(const float* p, float& d){
  unsigned long long a = (unsigned long long)p;
  asm volatile("global_load_dword %0, %1, off sc0 sc1" : "=v"(d) : "v"(a) : "memory");
}
__device__ __forceinline__ void vm_drain(){
  asm volatile("s_waitcnt vmcnt(0)" ::: "memory");
  __builtin_amdgcn_sched_barrier(0);
}

extern "C" __global__ void __launch_bounds__(256, 1) ea_lstm_fused(Params P){
  __shared__ __align__(16) unsigned short aLds[18432];   // [plane][p(<=36)][s32][j8]
  __shared__ __align__(16) float gdump[32 * 132];        // [s32][col128 +4 pad]
  __shared__ __align__(16) float redl[32 * 33];
  __shared__ __align__(16) unsigned short hstg[2 * 4 * 33 * 8]; // [plane2][kp4][s33][j8]

  const int tid = threadIdx.x;
  const int blk = blockIdx.x;
  const int sgp = blk & 7;    // sample group (XCD-affine)
  const int cbk = blk >> 3;   // column block 0..7 (128 gate cols each)
  const int lane = tid & 63;
  const int wv = tid >> 6;
  const int gtid = blk * 256 + tid;
  const int kgl = lane >> 5;
  const int aln = lane & 31;
  const int colg = cbk * 128 + wv * 32 + aln;

  // ---------------- precompute (all 64 blocks) ----------------
  {
    for (int e = gtid; e < 294912; e += 16384){           // EA weights [288 x 1024]
      int j = e & 7, kg = (e >> 3) & 1, col = (e >> 4) & 1023, kt = e >> 14;
      int k = kt * 16 + kg * 8 + j;
      int u = col >> 2, g = col & 3;
      const float* Wp = (g == 0) ? P.Wf : (g == 1) ? P.Wo : (g == 2) ? P.Wi : P.Wg;
      float w = Wp[u * 288 + k];
      unsigned short hi = f2bf(w);
      P.wpea_h[e] = hi; P.wpea_l[e] = f2bf(w - bf2f(hi));
    }
    for (int e = gtid; e < 524288; e += 16384){           // enc [512 x 1024]
      int j = e & 7, kg = (e >> 3) & 1, col = (e >> 4) & 1023, kt = e >> 14;
      int k = kt * 16 + kg * 8 + j;
      int u = col >> 2, g = col & 3, row = g * 256 + u;
      float w = (k < 256) ? P.eWih[row * 256 + k] : P.eWhh[row * 256 + (k - 256)];
      unsigned short hi = f2bf(w);
      P.wpenc_h[e] = hi; P.wpenc_l[e] = f2bf(w - bf2f(hi));
    }
    for (int e = gtid; e < 262144; e += 16384){           // dec0 [256 x 1024]
      int j = e & 7, kg = (e >> 3) & 1, col = (e >> 4) & 1023, kt = e >> 14;
      int k = kt * 16 + kg * 8 + j;
      int u = col >> 2, g = col & 3, row = g * 256 + u;
      float w = P.dWhh0[row * 256 + k];
      unsigned short hi = f2bf(w);
      P.wpd0_h[e] = hi; P.wpd0_l[e] = f2bf(w - bf2f(hi));
    }
    for (int e = gtid; e < 524288; e += 16384){           // dec1 [512 x 1024]
      int j = e & 7, kg = (e >> 3) & 1, col = (e >> 4) & 1023, kt = e >> 14;
      int k = kt * 16 + kg * 8 + j;
      int u = col >> 2, g = col & 3, row = g * 256 + u;
      float w = (k < 256) ? P.dWih1[row * 256 + k] : P.dWhh1[row * 256 + (k - 256)];
      unsigned short hi = f2bf(w);
      P.wpd1_h[e] = hi; P.wpd1_l[e] = f2bf(w - bf2f(hi));
    }
    for (int e = gtid; e < 2990080; e += 16384){          // x -> [t][kp4][s256][j8]
      int j = e & 7, sl = (e >> 3) & 255, kp = (e >> 11) & 3, t = e >> 13;
      int f = kp * 8 + j;
      float w = P.x[((size_t)sl * 365 + t) * 32 + f];
      unsigned short hi = f2bf(w);
      P.xp_h[e] = hi; P.xp_l[e] = f2bf(w - bf2f(hi));
    }
    for (int e = gtid; e < 65536; e += 16384){            // si/sg statics (incl. bi/bg)
      int u = e & 255, b = e >> 8;
      float ai = P.bsi[u] + P.bi[u];
      float ag = P.bsg[u] + P.bg[u];
      for (int k = 0; k < 27; ++k){
        float sv = P.s_in[b * 27 + k];
        ai += sv * P.Wsi[u * 27 + k];
        ag += sv * P.Wsg[u * 27 + k];
      }
      P.si_v[b * 256 + u] = ai;
      P.sg_v[b * 256 + u] = ag;
    }
    for (int e = gtid; e < 1024; e += 16384){             // col biases / vectors
      int u = e >> 2, g = e & 3, row = g * 256 + u;
      P.cbea[e] = (g == 0) ? P.bf[u] : (g == 1) ? P.bo[u] : 0.0f;
      P.cbenc[e] = P.ebih[row] + P.ebhh[row];
      P.cbd0[e]  = P.dbih0[row] + P.dbhh0[row];
      P.cbd1[e]  = P.dbih1[row] + P.dbhh1[row];
      P.w0v[e]   = P.dWih0[row];
      if (e < 256) P.fcw[e] = P.fcW[e];
    }
    for (int e = gtid; e < 6144; e += 16384) P.pred[e] = P.fcb[0];
  }

  // one-time global barrier (64 blocks, acq_rel: flushes precompute to mem-side)
  __syncthreads();
  if (tid == 0){
    unsigned n = __hip_atomic_fetch_add(P.ctrl, 1u, __ATOMIC_ACQ_REL, __HIP_MEMORY_SCOPE_AGENT) + 1u;
    if (n == 64u) __hip_atomic_store(P.ctrl + 16, 1u, __ATOMIC_RELEASE, __HIP_MEMORY_SCOPE_AGENT);
    else while (__hip_atomic_load(P.ctrl + 16, __ATOMIC_ACQUIRE, __HIP_MEMORY_SCOPE_AGENT) < 1u)
      __builtin_amdgcn_s_sleep(2);
  }
  __syncthreads();

  // ---------------- persistent phase machinery (relaxed, fence-free) ----------------
  unsigned* gctr = P.ctrl + 32 + 32 * sgp;
  unsigned gphase = 0;   // arrivals completed by THIS block

  const int u_loc = tid & 31;
  const int u_g = cbk * 32 + u_loc;
  int s_loc[4], s_g[4];
  #pragma unroll
  for (int q = 0; q < 4; ++q){ s_loc[q] = 8 * q + (tid >> 5); s_g[q] = sgp * 32 + s_loc[q]; }

  // tid0-only poll, then barrier releases the block.
  auto spinp = [&](){
    if (tid == 0){
      unsigned target = 8u * gphase;
      while (__hip_atomic_load(gctr, __ATOMIC_RELAXED, __HIP_MEMORY_SCOPE_SYSTEM) < target) {}
    }
    __syncthreads();
  };
  auto arrive = [&](){
    vm_drain();
    __syncthreads();
    if (tid == 0) __hip_atomic_fetch_add(gctr, 1u, __ATOMIC_RELAXED, __HIP_MEMORY_SCOPE_SYSTEM);
    ++gphase;
  };

  // stage a full 32-kp h slot via coherent loads (PC=32 layout)
  auto stage32_c = [&](const unsigned short* slot){
    u32x4 v[8];
    #pragma unroll
    for (int i = 0; i < 8; ++i){
      int seg = tid + 256 * i;
      int plane = seg >> 10, rem = seg & 1023, p = rem >> 5, sl = rem & 31;
      v[i] = ldg_cc16(slot + (size_t)plane * 65536 + (p * 256 + sgp * 32 + sl) * 8);
    }
    vm_drain();
    #pragma unroll
    for (int i = 0; i < 8; ++i){
      int seg = tid + 256 * i;
      int plane = seg >> 10, rem = seg & 1023, p = rem >> 5, sl = rem & 31;
      *(u32x4*)&aLds[((plane * 32 + p) * 32 + sl) * 8] = v[i];
    }
  };
  // EA: x part (kp 0..3 of 36) — static data, plain loads, 1 uint4/thread
  auto stage_ea_x = [&](int t){
    int plane = tid >> 7, p = (tid >> 5) & 3, sl = tid & 31;
    const unsigned short* xp = plane ? P.xp_l : P.xp_h;
    uint4 v = *(const uint4*)(xp + (size_t)t * 8192 + (p * 256 + sgp * 32 + sl) * 8);
    *(uint4*)&aLds[((plane * 36 + p) * 32 + sl) * 8] = v;
  };
  // EA: h part (kp 4..35 of 36) — coherent loads, zeros at t=0
  auto stage_ea_h = [&](const unsigned short* hslot){
    if (hslot){
      u32x4 v[8];
      #pragma unroll
      for (int i = 0; i < 8; ++i){
        int seg = tid + 256 * i;
        int plane = seg >> 10, rem = seg & 1023, hp = rem >> 5, sl = rem & 31;
        v[i] = ldg_cc16(hslot + (size_t)plane * 65536 + (hp * 256 + sgp * 32 + sl) * 8);
      }
      vm_drain();
      #pragma unroll
      for (int i = 0; i < 8; ++i){
        int seg = tid + 256 * i;
        int plane = seg >> 10, rem = seg & 1023, hp = rem >> 5, sl = rem & 31;
        *(u32x4*)&aLds[((plane * 36 + 4 + hp) * 32 + sl) * 8] = v[i];
      }
    } else {
      u32x4 z = {0u, 0u, 0u, 0u};
      #pragma unroll
      for (int i = 0; i < 8; ++i){
        int seg = tid + 256 * i;
        int plane = seg >> 10, rem = seg & 1023, hp = rem >> 5, sl = rem & 31;
        *(u32x4*)&aLds[((plane * 36 + 4 + hp) * 32 + sl) * 8] = z;
      }
    }
  };

  // streaming-weight MFMA (kept for decoder phase only — 48 rounds, negligible)
  auto mfma_chunk = [&](f32x16 acc, const unsigned short* wh, const unsigned short* wl,
                        int nkt, int kt0, int PC) -> f32x16 {
    #pragma unroll 4
    for (int kt = 0; kt < nkt; ++kt){
      int p = 2 * kt + kgl;
      bf16x8 ahi = __builtin_bit_cast(bf16x8, *(const uint4*)&aLds[((0 * PC + p) * 32 + aln) * 8]);
      bf16x8 alo = __builtin_bit_cast(bf16x8, *(const uint4*)&aLds[((1 * PC + p) * 32 + aln) * 8]);
      size_t be = ((size_t)(kt + kt0) * 1024 + colg) * 16 + kgl * 8;
      bf16x8 bhi = __builtin_bit_cast(bf16x8, *(const uint4*)(wh + be));
      bf16x8 blo = __builtin_bit_cast(bf16x8, *(const uint4*)(wl + be));
      acc = __builtin_amdgcn_mfma_f32_32x32x16_bf16(alo, bhi, acc, 0, 0, 0);
      acc = __builtin_amdgcn_mfma_f32_32x32x16_bf16(ahi, blo, acc, 0, 0, 0);
      acc = __builtin_amdgcn_mfma_f32_32x32x16_bf16(ahi, bhi, acc, 0, 0, 0);
    }
    return acc;
  };

  auto dump = [&](const f32x16& acc){
    #pragma unroll
    for (int r = 0; r < 16; ++r){
      int row = (r & 3) + 8 * (r >> 2) + 4 * kgl;    // verified C/D layout
      gdump[row * 132 + wv * 32 + aln] = acc[r];
    }
  };

  // scatter h (bf16 hi/lo) into hstg (padded s-stride 33)
  auto h_scatter = [&](int q, float h){
    int kp = u_loc >> 3, j = u_loc & 7;
    unsigned short hi = f2bf(h);
    hstg[((0 * 4 + kp) * 33 + s_loc[q]) * 8 + j] = hi;
    hstg[((1 * 4 + kp) * 33 + s_loc[q]) * 8 + j] = f2bf(h - bf2f(hi));
  };
  // coalesced 16B coherent store of the block's h tile (call after __syncthreads)
  auto h_store = [&](unsigned short* slot){
    int plane = tid >> 7, kp = (tid >> 5) & 3, sl = tid & 31;
    u32x4 v = *(const u32x4*)&hstg[((plane * 4 + kp) * 33 + sl) * 8];
    stg_cc16(slot + (size_t)plane * 65536 + (((size_t)(cbk * 4 + kp) * 256) + sgp * 32 + sl) * 8, v);
  };

  float cbr[4];
  float cst[4] = {0.f, 0.f, 0.f, 0.f};

  // ---------------- EA phase ----------------
  {
    float sir[4], sgr[4];
    #pragma unroll
    for (int g = 0; g < 4; ++g) cbr[g] = P.cbea[4 * u_g + g];
    #pragma unroll
    for (int q = 0; q < 4; ++q){
      sir[q] = P.si_v[s_g[q] * 256 + u_g];
      sgr[q] = P.sg_v[s_g[q] * 256 + u_g];
    }
    // hold this block's EA weight slice in VGPRs (36 x bf16x8 = 144 VGPR):
    // removes the per-round L2 weight stream from the critical path.
    bf16x8 wea[36];
    #pragma unroll
    for (int kt = 0; kt < 18; ++kt){
      size_t be = ((size_t)kt * 1024 + colg) * 16 + (size_t)(kgl * 8);
      wea[2 * kt]     = __builtin_bit_cast(bf16x8, *(const uint4*)(P.wpea_h + be));
      wea[2 * kt + 1] = __builtin_bit_cast(bf16x8, *(const uint4*)(P.wpea_l + be));
    }
    for (int t = 0; t < 365; ++t){
      stage_ea_x(t);                      // flag-independent
      spinp();                            // wait h(t-1) from all blocks
      stage_ea_h(t ? P.hseq + (size_t)(t - 1) * SLOT : nullptr);
      __syncthreads();
      f32x16 acc;
      #pragma unroll
      for (int r = 0; r < 16; ++r) acc[r] = 0.0f;
      #pragma unroll
      for (int kt = 0; kt < 18; ++kt){    // full unroll: static wea indices
        int p = 2 * kt + kgl;
        bf16x8 ahi = __builtin_bit_cast(bf16x8, *(const uint4*)&aLds[((0 * 36 + p) * 32 + aln) * 8]);
        bf16x8 alo = __builtin_bit_cast(bf16x8, *(const uint4*)&aLds[((1 * 36 + p) * 32 + aln) * 8]);
        acc = __builtin_amdgcn_mfma_f32_32x32x16_bf16(alo, wea[2 * kt], acc, 0, 0, 0);
        acc = __builtin_amdgcn_mfma_f32_32x32x16_bf16(ahi, wea[2 * kt + 1], acc, 0, 0, 0);
        acc = __builtin_amdgcn_mfma_f32_32x32x16_bf16(ahi, wea[2 * kt], acc, 0, 0, 0);
      }
      dump(acc); __syncthreads();
      #pragma unroll
      for (int q = 0; q < 4; ++q){
        float4 g4 = *(const float4*)&gdump[s_loc[q] * 132 + 4 * u_loc];
        float f = sigm(g4.x + cbr[0]);
        float o = sigm(g4.y + cbr[1]);
        float i = sigm(g4.z + sir[q]);
        float g = tanh_f(g4.w + sgr[q]);
        float c = f * cst[q] + i * g;
        cst[q] = c;
        h_scatter(q, o * tanh_f(c));
      }
      __syncthreads();
      h_store(P.hseq + (size_t)t * SLOT);
      arrive();
    }
  }

  // ---------------- encoder phase ----------------
  {
    #pragma unroll
    for (int g = 0; g < 4; ++g) cbr[g] = P.cbenc[4 * u_g + g];
    // hold enc weight slice in VGPRs (64 x bf16x8 = 256 VGPR)
    bf16x8 wenc[64];
    #pragma unroll
    for (int kt = 0; kt < 32; ++kt){
      size_t be = ((size_t)kt * 1024 + colg) * 16 + (size_t)(kgl * 8);
      wenc[2 * kt]     = __builtin_bit_cast(bf16x8, *(const uint4*)(P.wpenc_h + be));
      wenc[2 * kt + 1] = __builtin_bit_cast(bf16x8, *(const uint4*)(P.wpenc_l + be));
    }
    for (int t = 0; t < 365; ++t){
      // first half: Wih * ea_seq[t] — flag-independent (hseq[t] is final since EA)
      stage32_c(P.hseq + (size_t)t * SLOT); __syncthreads();
      f32x16 acc;
      #pragma unroll
      for (int r = 0; r < 16; ++r) acc[r] = 0.0f;
      #pragma unroll
      for (int k = 0; k < 16; ++k){
        int p = 2 * k + kgl;
        bf16x8 ahi = __builtin_bit_cast(bf16x8, *(const uint4*)&aLds[((0 * 32 + p) * 32 + aln) * 8]);
        bf16x8 alo = __builtin_bit_cast(bf16x8, *(const uint4*)&aLds[((1 * 32 + p) * 32 + aln) * 8]);
        acc = __builtin_amdgcn_mfma_f32_32x32x16_bf16(alo, wenc[2 * k], acc, 0, 0, 0);
        acc = __builtin_amdgcn_mfma_f32_32x32x16_bf16(ahi, wenc[2 * k + 1], acc, 0, 0, 0);
        acc = __builtin_amdgcn_mfma_f32_32x32x16_bf16(ahi, wenc[2 * k], acc, 0, 0, 0);
      }
      __syncthreads();                    // all waves done with aLds
      spinp();                            // wait h_enc(t-1)
      stage32_c(t ? P.henc + (size_t)((t - 1) & 1) * SLOT
                  : P.hseq + (size_t)364 * SLOT);
      __syncthreads();
      #pragma unroll
      for (int k = 0; k < 16; ++k){       // second half: Whh * h_enc(t-1)
        int p = 2 * k + kgl;
        bf16x8 ahi = __builtin_bit_cast(bf16x8, *(const uint4*)&aLds[((0 * 32 + p) * 32 + aln) * 8]);
        bf16x8 alo = __builtin_bit_cast(bf16x8, *(const uint4*)&aLds[((1 * 32 + p) * 32 + aln) * 8]);
        acc = __builtin_amdgcn_mfma_f32_32x32x16_bf16(alo, wenc[32 + 2 * k], acc, 0, 0, 0);
        acc = __builtin_amdgcn_mfma_f32_32x32x16_bf16(ahi, wenc[32 + 2 * k + 1], acc, 0, 0, 0);
        acc = __builtin_amdgcn_mfma_f32_32x32x16_bf16(ahi, wenc[32 + 2 * k], acc, 0, 0, 0);
      }
      dump(acc); __syncthreads();
      #pragma unroll
      for (int q = 0; q < 4; ++q){
        float4 g4 = *(const float4*)&gdump[s_loc[q] * 132 + 4 * u_loc];
        float i = sigm(g4.x + cbr[0]);
        float f = sigm(g4.y + cbr[1]);
        float g = tanh_f(g4.z + cbr[2]);
        float o = sigm(g4.w + cbr[3]);
        float c = f * cst[q] + i * g;
        cst[q] = c;
        h_scatter(q, o * tanh_f(c));
      }
      __syncthreads();
      h_store(P.henc + (size_t)(t & 1) * SLOT);
      arrive();
    }
  }

  // ---------------- decoder phase (streaming weights — only 48 rounds) ----------------
  {
    float cb0r[4], cb1r[4], w0r[4];
    #pragma unroll
    for (int g = 0; g < 4; ++g){
      cb0r[g] = P.cbd0[4 * u_g + g];
      cb1r[g] = P.cbd1[4 * u_g + g];
      w0r[g]  = P.w0v[4 * u_g + g];
    }
    float fcwr = P.fcw[u_g];
    float cA[4], cB[4];
    #pragma unroll
    for (int q = 0; q < 4; ++q){ cA[q] = cst[q]; cB[q] = cst[q]; }

    spinp();   // ensure enc final h (henc slot 0) visible before t=0 staging

    for (int t = 0; t < 24; ++t){
      // ---- cell 0: entire GEMM is flag-independent (hA(t-1) two arrivals old) ----
      stage32_c(t ? P.hA + (size_t)((t - 1) & 1) * SLOT : P.henc);
      __syncthreads();
      f32x16 acc;
      #pragma unroll
      for (int r = 0; r < 16; ++r) acc[r] = 0.0f;
      acc = mfma_chunk(acc, P.wpd0_h, P.wpd0_l, 16, 0, 32);
      dump(acc); __syncthreads();
      spinp();                            // wait cell1(t-1): pred(t-1) ready
      float d0 = 0.f, d1 = 0.f, d2 = 0.f, d3 = 0.f;
      if (t){
        ldg_f32_issue(&P.pred[(t - 1) * 256 + s_g[0]], d0);
        ldg_f32_issue(&P.pred[(t - 1) * 256 + s_g[1]], d1);
        ldg_f32_issue(&P.pred[(t - 1) * 256 + s_g[2]], d2);
        ldg_f32_issue(&P.pred[(t - 1) * 256 + s_g[3]], d3);
        asm volatile("s_waitcnt vmcnt(0)" : "+v"(d0), "+v"(d1), "+v"(d2), "+v"(d3) :: "memory");
        __builtin_amdgcn_sched_barrier(0);
      }
      float din[4] = {d0, d1, d2, d3};
      #pragma unroll
      for (int q = 0; q < 4; ++q){
        float4 g4 = *(const float4*)&gdump[s_loc[q] * 132 + 4 * u_loc];
        float i = sigm(g4.x + cb0r[0] + din[q] * w0r[0]);
        float f = sigm(g4.y + cb0r[1] + din[q] * w0r[1]);
        float g = tanh_f(g4.z + cb0r[2] + din[q] * w0r[2]);
        float o = sigm(g4.w + cb0r[3] + din[q] * w0r[3]);
        float c = f * cA[q] + i * g;
        cA[q] = c;
        h_scatter(q, o * tanh_f(c));
      }
      __syncthreads();
      h_store(P.hA + (size_t)(t & 1) * SLOT);
      arrive();

      // ---- cell 1: hB(t-1) half is flag-independent; hA(t) half waits cell0(t) ----
      stage32_c(t ? P.hB + (size_t)((t - 1) & 1) * SLOT : P.henc);
      __syncthreads();
      #pragma unroll
      for (int r = 0; r < 16; ++r) acc[r] = 0.0f;
      acc = mfma_chunk(acc, P.wpd1_h, P.wpd1_l, 16, 16, 32);   // Whh1 * hB(t-1)
      __syncthreads();
      spinp();                            // wait cell0(t): hA(t) ready
      stage32_c(P.hA + (size_t)(t & 1) * SLOT);
      __syncthreads();
      acc = mfma_chunk(acc, P.wpd1_h, P.wpd1_l, 16, 0, 32);    // Wih1 * hA(t)
      dump(acc); __syncthreads();
      #pragma unroll
      for (int q = 0; q < 4; ++q){
        float4 g4 = *(const float4*)&gdump[s_loc[q] * 132 + 4 * u_loc];
        float i = sigm(g4.x + cb1r[0]);
        float f = sigm(g4.y + cb1r[1]);
        float g = tanh_f(g4.z + cb1r[2]);
        float o = sigm(g4.w + cb1r[3]);
        float c = f * cB[q] + i * g;
        cB[q] = c;
        float h = o * tanh_f(c);
        h_scatter(q, h);
        redl[u_loc * 33 + s_loc[q]] = fcwr * h;
      }
      __syncthreads();
      h_store(P.hB + (size_t)(t & 1) * SLOT);
      if (tid < 32){
        float sum = 0.0f;
        #pragma unroll
        for (int u = 0; u < 32; ++u) sum += redl[u * 33 + tid];
        __hip_atomic_fetch_add(&P.pred[t * 256 + sgp * 32 + tid], sum,
                               __ATOMIC_RELAXED, __HIP_MEMORY_SCOPE_SYSTEM);
      }
      arrive();
    }
  }

  // ---------------- output ----------------
  spinp();   // ALL blocks wait for everyone's final arrive (pred[23] complete)
  if (cbk == 0){
    for (int i = tid; i < 32 * 24; i += 256){
      int sl = i / 24, tt = i % 24;
      float v = 0.0f;
      ldg_f32_issue(&P.pred[tt * 256 + sgp * 32 + sl], v);
      asm volatile("s_waitcnt vmcnt(0)" : "+v"(v) :: "memory");
      P.out[(size_t)(sgp * 32 + sl) * 24 + tt] = v;
    }
  }
}

extern "C" void kernel_launch(void* const* d_in, const int* in_sizes, int n_in,
                              void* d_out, int out_size, void* d_ws, size_t ws_size,
                              hipStream_t stream){
  (void)in_sizes; (void)n_in; (void)out_size; (void)ws_size;
  Params P;
  P.x = (const float*)d_in[0];   P.s_in = (const float*)d_in[1];
  P.Wf = (const float*)d_in[2];  P.bf = (const float*)d_in[3];
  P.Wo = (const float*)d_in[4];  P.bo = (const float*)d_in[5];
  P.Wi = (const float*)d_in[6];  P.bi = (const float*)d_in[7];
  P.Wg = (const float*)d_in[8];  P.bg = (const float*)d_in[9];
  P.Wsi = (const float*)d_in[10]; P.bsi = (const float*)d_in[11];
  P.Wsg = (const float*)d_in[12]; P.bsg = (const float*)d_in[13];
  P.eWih = (const float*)d_in[14]; P.eWhh = (const float*)d_in[15];
  P.ebih = (const float*)d_in[16]; P.ebhh = (const float*)d_in[17];
  P.dWih0 = (const float*)d_in[18]; P.dWhh0 = (const float*)d_in[19];
  P.dbih0 = (const float*)d_in[20]; P.dbhh0 = (const float*)d_in[21];
  P.dWih1 = (const float*)d_in[22]; P.dWhh1 = (const float*)d_in[23];
  P.dbih1 = (const float*)d_in[24]; P.dbhh1 = (const float*)d_in[25];
  P.fcW = (const float*)d_in[26]; P.fcb = (const float*)d_in[27];
  P.out = (float*)d_out;

  char* base = (char*)d_ws;
  size_t off = 0;
  auto take = [&](size_t bytes) -> char* {
    char* r = base + off;
    off = (off + bytes + 255) & ~(size_t)255;
    return r;
  };
  P.ctrl    = (unsigned*)take(4096);
  P.wpea_h  = (unsigned short*)take((size_t)294912 * 2);
  P.wpea_l  = (unsigned short*)take((size_t)294912 * 2);
  P.wpenc_h = (unsigned short*)take((size_t)524288 * 2);
  P.wpenc_l = (unsigned short*)take((size_t)524288 * 2);
  P.wpd0_h  = (unsigned short*)take((size_t)262144 * 2);
  P.wpd0_l  = (unsigned short*)take((size_t)262144 * 2);
  P.wpd1_h  = (unsigned short*)take((size_t)524288 * 2);
  P.wpd1_l  = (unsigned short*)take((size_t)524288 * 2);
  P.xp_h    = (unsigned short*)take((size_t)2990080 * 2);
  P.xp_l    = (unsigned short*)take((size_t)2990080 * 2);
  P.si_v    = (float*)take((size_t)65536 * 4);
  P.sg_v    = (float*)take((size_t)65536 * 4);
  P.cbea    = (float*)take(4096);
  P.cbenc   = (float*)take(4096);
  P.cbd0    = (float*)take(4096);
  P.cbd1    = (float*)take(4096);
  P.w0v     = (float*)take(4096);
  P.fcw     = (float*)take(1024);
  P.pred    = (float*)take((size_t)6144 * 4);
  P.henc    = (unsigned short*)take((size_t)2 * 131072 * 2);
  P.hA      = (unsigned short*)take((size_t)2 * 131072 * 2);
  P.hB      = (unsigned short*)take((size_t)2 * 131072 * 2);
  P.hseq    = (unsigned short*)take((size_t)365 * 131072 * 2);

  hipMemsetAsync(d_ws, 0, 4096, stream);
  hipLaunchKernelGGL(ea_lstm_fused, dim3(64), dim3(256), 0, stream, P);
}